// Round 3
// baseline (51.413 us; speedup 1.0000x reference)
//
#include <hip/hip_runtime.h>
#include <hip/hip_bf16.h>

#define BATCH 8192
#define DDIM 512
#define FDIM 64
#define KD 64

typedef __attribute__((ext_vector_type(8))) short short8;
typedef __attribute__((ext_vector_type(4))) float f32x4;

static __device__ __forceinline__ unsigned short f2bf(float f) {
    __hip_bfloat16 h = __float2bfloat16(f);
    return *reinterpret_cast<unsigned short*>(&h);
}

// ---------------- W^T (bf16, N-major) + zero out ----------------
// Block per j. WT[j*D + i] = (i<j) ? dot(kernel[i,fd[j],:], kernel[j,fd[i],:]) : 0
__global__ __launch_bounds__(256) void w_kernel(const float* __restrict__ kern,
                                                const int* __restrict__ fd,
                                                unsigned short* __restrict__ WT,
                                                float* __restrict__ out) {
    const int j = blockIdx.x;
    const int tid = threadIdx.x;

    __shared__ float Bv[FDIM * KD];   // kernel[j,:,:]  (16 KB)
    __shared__ int fds[DDIM];

    if (tid < 16) out[j * 16 + tid] = 0.f;   // fold out-zeroing in (runs before quad)

    {
        const float4* src = reinterpret_cast<const float4*>(kern + (size_t)j * FDIM * KD);
        float4* dst = reinterpret_cast<float4*>(Bv);
#pragma unroll
        for (int u = 0; u < 4; ++u) dst[u * 256 + tid] = src[u * 256 + tid];
        fds[tid] = fd[tid];
        fds[tid + 256] = fd[tid + 256];
    }
    __syncthreads();

    const int fdj = fds[j];
    const int g = tid >> 4;    // 16-lane group -> one i per iteration
    const int gl = tid & 15;   // lane over k (4 floats each)

#pragma unroll 2
    for (int it = 0; it < DDIM / 16; ++it) {
        const int i = it * 16 + g;
        float s = 0.f;
        if (i < j) {
            float4 a = *reinterpret_cast<const float4*>(kern + ((size_t)i * FDIM + fdj) * KD + gl * 4);
            float4 b = *reinterpret_cast<const float4*>(Bv + fds[i] * KD + gl * 4);
            s = a.x * b.x + a.y * b.y + a.z * b.z + a.w * b.w;
        }
#pragma unroll
        for (int off = 1; off < 16; off <<= 1) s += __shfl_xor(s, off);
        if (gl == 0) WT[(size_t)j * DDIM + i] = f2bf(s);
    }
}

// ---------------- fused  out[b] = x[b,:] @ Wm @ x[b,:]  (MFMA bf16) ----------------
#define BM 64
#define BN 128
#define BK 64
#define NIT (DDIM / BK)

__global__ __launch_bounds__(256, 2) void quad_kernel(const float* __restrict__ x,
                                                      const unsigned short* __restrict__ WT,
                                                      float* __restrict__ out) {
    __shared__ unsigned short As[2][BM * BK];   // 16 KB  (16B-chunk XOR swizzle)
    __shared__ unsigned short Bs[2][BN * BK];   // 32 KB

    const int tid = threadIdx.x;
    const int lane = tid & 63;
    const int w = tid >> 6;
    const int wm = w >> 1, wn = w & 1;
    const int ln = lane & 15, l4 = lane >> 4;
    const int nbase = blockIdx.x * BN;   // grid.x = N-blocks (4): row-sharing blocks adjacent
    const int mbase = blockIdx.y * BM;

    f32x4 acc[2][4] = {};

    const int srow = tid >> 2;   // 0..63
    const int sc = tid & 3;

    float4 areg[2][4];
    int4 breg[2][4];

    auto loadA = [&](int kk, int rb) {
        const float4* src = reinterpret_cast<const float4*>(x + (size_t)(mbase + srow) * DDIM + kk + sc * 16);
#pragma unroll
        for (int u = 0; u < 4; ++u) areg[rb][u] = src[u];
    };
    auto loadB = [&](int kk, int rb) {
#pragma unroll
        for (int r = 0; r < 2; ++r) {
            const int4* src = reinterpret_cast<const int4*>(WT + (size_t)(nbase + srow + r * 64) * DDIM + kk);
#pragma unroll
            for (int u = 0; u < 2; ++u) breg[rb][r * 2 + u] = src[sc * 2 + u];
        }
    };
    auto writeTile = [&](int rb, int lb) {
#pragma unroll
        for (int h = 0; h < 2; ++h) {
            float4 p = areg[rb][2 * h], q = areg[rb][2 * h + 1];
            short8 v;
            v[0] = (short)f2bf(p.x); v[1] = (short)f2bf(p.y);
            v[2] = (short)f2bf(p.z); v[3] = (short)f2bf(p.w);
            v[4] = (short)f2bf(q.x); v[5] = (short)f2bf(q.y);
            v[6] = (short)f2bf(q.z); v[7] = (short)f2bf(q.w);
            int chunk = (2 * sc + h) ^ (srow & 7);
            *reinterpret_cast<short8*>(&As[lb][srow * BK + chunk * 8]) = v;
        }
#pragma unroll
        for (int r = 0; r < 2; ++r)
#pragma unroll
            for (int u = 0; u < 2; ++u) {
                int row = srow + r * 64;
                int chunk = (2 * sc + u) ^ (row & 7);
                *reinterpret_cast<int4*>(&Bs[lb][row * BK + chunk * 8]) = breg[rb][r * 2 + u];
            }
    };

    // prologue: tile0 -> regs -> LDS buf0; tile1 -> regs (in flight)
    loadA(0, 0); loadB(0, 0);
    loadA(BK, 1); loadB(BK, 1);
    writeTile(0, 0);
    __syncthreads();

    for (int t = 0; t < NIT; ++t) {
        if (t + 2 < NIT) { loadA((t + 2) * BK, t & 1); loadB((t + 2) * BK, t & 1); }

        const int lb = t & 1;
        short8 a[2][2], b[2][4];
#pragma unroll
        for (int ks = 0; ks < 2; ++ks) {
#pragma unroll
            for (int m = 0; m < 2; ++m) {
                int row = wm * 32 + m * 16 + ln;
                int chunk = (ks * 4 + l4) ^ (row & 7);
                a[ks][m] = *reinterpret_cast<const short8*>(&As[lb][row * BK + chunk * 8]);
            }
#pragma unroll
            for (int n = 0; n < 4; ++n) {
                int col = wn * 64 + n * 16 + ln;
                int chunk = (ks * 4 + l4) ^ (col & 7);
                b[ks][n] = *reinterpret_cast<const short8*>(&Bs[lb][col * BK + chunk * 8]);
            }
        }
#pragma unroll
        for (int ks = 0; ks < 2; ++ks)
#pragma unroll
            for (int m = 0; m < 2; ++m)
#pragma unroll
                for (int n = 0; n < 4; ++n)
                    acc[m][n] = __builtin_amdgcn_mfma_f32_16x16x32_bf16(a[ks][m], b[ks][n], acc[m][n], 0, 0, 0);

        if (t + 1 < NIT) writeTile((t + 1) & 1, (t + 1) & 1);
        __syncthreads();
    }

    // epilogue: out[row] += sum_col y[row][col] * x[row][col]
#pragma unroll
    for (int m = 0; m < 2; ++m) {
#pragma unroll
        for (int q = 0; q < 4; ++q) {
            int grow = mbase + wm * 32 + m * 16 + l4 * 4 + q;   // C/D: row=(lane>>4)*4+reg
            float s = 0.f;
#pragma unroll
            for (int n = 0; n < 4; ++n) {
                int gcol = nbase + wn * 64 + n * 16 + ln;        // C/D: col=lane&15
                s += acc[m][n][q] * x[(size_t)grow * DDIM + gcol];
            }
#pragma unroll
            for (int off = 1; off < 16; off <<= 1)
                s += __shfl_xor(s, off, 64);
            if (ln == 0) atomicAdd(out + grow, s);
        }
    }
}

extern "C" void kernel_launch(void* const* d_in, const int* in_sizes, int n_in,
                              void* d_out, int out_size, void* d_ws, size_t ws_size,
                              hipStream_t stream) {
    const float* x = (const float*)d_in[0];
    const float* kern = (const float*)d_in[1];
    const int* fd = (const int*)d_in[2];
    float* out = (float*)d_out;

    unsigned short* WT = (unsigned short*)d_ws;

    w_kernel<<<DDIM, 256, 0, stream>>>(kern, fd, WT, out);
    dim3 qgrid(DDIM / BN, BATCH / BM);
    quad_kernel<<<qgrid, 256, 0, stream>>>(x, WT, out);
}

// Round 7
// 50.353 us; speedup vs baseline: 1.0211x; 1.0211x over previous
//
#include <hip/hip_runtime.h>
#include <hip/hip_bf16.h>

#define BATCH 8192
#define DDIM 512
#define FDIM 64
#define KD 64

typedef __attribute__((ext_vector_type(8))) short short8;
typedef __attribute__((ext_vector_type(4))) float f32x4;

static __device__ __forceinline__ unsigned short f2bf(float f) {
    __hip_bfloat16 h = __float2bfloat16(f);
    return *reinterpret_cast<unsigned short*>(&h);
}

// ---------------- W^T (bf16, N-major) + zero out ----------------
// Block per j. WT[j*D + i] = (i<j) ? dot(kernel[i,fd[j],:], kernel[j,fd[i],:]) : 0
__global__ __launch_bounds__(256) void w_kernel(const float* __restrict__ kern,
                                                const int* __restrict__ fd,
                                                unsigned short* __restrict__ WT,
                                                float* __restrict__ out) {
    const int j = blockIdx.x;
    const int tid = threadIdx.x;

    __shared__ float Bv[FDIM * KD];   // kernel[j,:,:]  (16 KB)
    __shared__ int fds[DDIM];

    if (tid < 16) out[j * 16 + tid] = 0.f;   // fold out-zeroing in (runs before quad)

    {
        const float4* src = reinterpret_cast<const float4*>(kern + (size_t)j * FDIM * KD);
        float4* dst = reinterpret_cast<float4*>(Bv);
#pragma unroll
        for (int u = 0; u < 4; ++u) dst[u * 256 + tid] = src[u * 256 + tid];
        fds[tid] = fd[tid];
        fds[tid + 256] = fd[tid + 256];
    }
    __syncthreads();

    const int fdj = fds[j];
    const int g = tid >> 4;    // 16-lane group -> one i per iteration
    const int gl = tid & 15;   // lane over k (4 floats each)

#pragma unroll 2
    for (int it = 0; it < DDIM / 16; ++it) {
        const int i = it * 16 + g;
        float s = 0.f;
        if (i < j) {
            float4 a = *reinterpret_cast<const float4*>(kern + ((size_t)i * FDIM + fdj) * KD + gl * 4);
            float4 b = *reinterpret_cast<const float4*>(Bv + fds[i] * KD + gl * 4);
            s = a.x * b.x + a.y * b.y + a.z * b.z + a.w * b.w;
        }
#pragma unroll
        for (int off = 1; off < 16; off <<= 1) s += __shfl_xor(s, off);
        if (gl == 0) WT[(size_t)j * DDIM + i] = f2bf(s);
    }
}

// ---------------- fused  out[b] = x[b,:] @ Wm @ x[b,:]  (MFMA bf16) ----------------
#define BM 64
#define BN 128
#define BK 64
#define NIT (DDIM / BK)

__global__ __launch_bounds__(256, 2) void quad_kernel(const float* __restrict__ x,
                                                      const unsigned short* __restrict__ WT,
                                                      float* __restrict__ out) {
    __shared__ unsigned short As[2][BM * BK];   // 16 KB  (16B-chunk XOR swizzle)
    __shared__ unsigned short Bs[2][BN * BK];   // 32 KB

    const int tid = threadIdx.x;
    const int lane = tid & 63;
    const int w = tid >> 6;
    const int wm = w >> 1, wn = w & 1;
    const int ln = lane & 15, l4 = lane >> 4;
    const int nbase = blockIdx.x * BN;   // grid.x = N-blocks (4): row-sharing blocks adjacent
    const int mbase = blockIdx.y * BM;

    f32x4 acc[2][4] = {};

    const int srow = tid >> 2;   // 0..63
    const int sc = tid & 3;

    // Named double buffers: ALL indices compile-time (rule #20 — no scratch).
    float4 aregA[4], aregB[4];
    int4 bregA[4], bregB[4];

    auto loadTile = [&](int kk, float4 (&ar)[4], int4 (&br)[4]) {
        const float4* srcA = reinterpret_cast<const float4*>(x + (size_t)(mbase + srow) * DDIM + kk + sc * 16);
#pragma unroll
        for (int u = 0; u < 4; ++u) ar[u] = srcA[u];
#pragma unroll
        for (int r = 0; r < 2; ++r) {
            const int4* srcB = reinterpret_cast<const int4*>(WT + (size_t)(nbase + srow + r * 64) * DDIM + kk);
#pragma unroll
            for (int u = 0; u < 2; ++u) br[r * 2 + u] = srcB[sc * 2 + u];
        }
    };
    auto writeTile = [&](float4 (&ar)[4], int4 (&br)[4], unsigned short* Asb, unsigned short* Bsb) {
#pragma unroll
        for (int h = 0; h < 2; ++h) {
            float4 p = ar[2 * h], q = ar[2 * h + 1];
            short8 v;
            v[0] = (short)f2bf(p.x); v[1] = (short)f2bf(p.y);
            v[2] = (short)f2bf(p.z); v[3] = (short)f2bf(p.w);
            v[4] = (short)f2bf(q.x); v[5] = (short)f2bf(q.y);
            v[6] = (short)f2bf(q.z); v[7] = (short)f2bf(q.w);
            int chunk = (2 * sc + h) ^ (srow & 7);
            *reinterpret_cast<short8*>(Asb + srow * BK + chunk * 8) = v;
        }
#pragma unroll
        for (int r = 0; r < 2; ++r)
#pragma unroll
            for (int u = 0; u < 2; ++u) {
                int row = srow + r * 64;
                int chunk = (2 * sc + u) ^ (row & 7);
                *reinterpret_cast<int4*>(Bsb + row * BK + chunk * 8) = br[r * 2 + u];
            }
    };
    auto computeTile = [&](const unsigned short* Asb, const unsigned short* Bsb) {
        short8 a[2][2], b[2][4];
#pragma unroll
        for (int ks = 0; ks < 2; ++ks) {
#pragma unroll
            for (int m = 0; m < 2; ++m) {
                int row = wm * 32 + m * 16 + ln;
                int chunk = (ks * 4 + l4) ^ (row & 7);
                a[ks][m] = *reinterpret_cast<const short8*>(Asb + row * BK + chunk * 8);
            }
#pragma unroll
            for (int n = 0; n < 4; ++n) {
                int col = wn * 64 + n * 16 + ln;
                int chunk = (ks * 4 + l4) ^ (col & 7);
                b[ks][n] = *reinterpret_cast<const short8*>(Bsb + col * BK + chunk * 8);
            }
        }
#pragma unroll
        for (int ks = 0; ks < 2; ++ks)
#pragma unroll
            for (int m = 0; m < 2; ++m)
#pragma unroll
                for (int n = 0; n < 4; ++n)
                    acc[m][n] = __builtin_amdgcn_mfma_f32_16x16x32_bf16(a[ks][m], b[ks][n], acc[m][n], 0, 0, 0);
    };

    // prologue: tile0 -> regsA -> LDS0; tile1 -> regsB (in flight)
    loadTile(0, aregA, bregA);
    loadTile(BK, aregB, bregB);
    writeTile(aregA, bregA, &As[0][0], &Bs[0][0]);
    __syncthreads();

    for (int t = 0; t < NIT; t += 2) {
        // even step: compute LDS0(tile t); prefetch tile t+2 -> regsA; write regsB(tile t+1) -> LDS1
        if (t + 2 < NIT) loadTile((t + 2) * BK, aregA, bregA);
        computeTile(&As[0][0], &Bs[0][0]);
        if (t + 1 < NIT) writeTile(aregB, bregB, &As[1][0], &Bs[1][0]);
        __syncthreads();
        // odd step: compute LDS1(tile t+1); prefetch tile t+3 -> regsB; write regsA(tile t+2) -> LDS0
        if (t + 3 < NIT) loadTile((t + 3) * BK, aregB, bregB);
        computeTile(&As[1][0], &Bs[1][0]);
        if (t + 2 < NIT) writeTile(aregA, bregA, &As[0][0], &Bs[0][0]);
        __syncthreads();
    }

    // epilogue: out[row] += sum_col y[row][col] * x[row][col]
#pragma unroll
    for (int m = 0; m < 2; ++m) {
#pragma unroll
        for (int q = 0; q < 4; ++q) {
            int grow = mbase + wm * 32 + m * 16 + l4 * 4 + q;   // C/D: row=(lane>>4)*4+reg
            float s = 0.f;
#pragma unroll
            for (int n = 0; n < 4; ++n) {
                int gcol = nbase + wn * 64 + n * 16 + ln;        // C/D: col=lane&15
                s += acc[m][n][q] * x[(size_t)grow * DDIM + gcol];
            }
#pragma unroll
            for (int off = 1; off < 16; off <<= 1)
                s += __shfl_xor(s, off, 64);
            if (ln == 0) atomicAdd(out + grow, s);
        }
    }
}

extern "C" void kernel_launch(void* const* d_in, const int* in_sizes, int n_in,
                              void* d_out, int out_size, void* d_ws, size_t ws_size,
                              hipStream_t stream) {
    const float* x = (const float*)d_in[0];
    const float* kern = (const float*)d_in[1];
    const int* fd = (const int*)d_in[2];
    float* out = (float*)d_out;

    unsigned short* WT = (unsigned short*)d_ws;

    w_kernel<<<DDIM, 256, 0, stream>>>(kern, fd, WT, out);
    dim3 qgrid(DDIM / BN, BATCH / BM);
    quad_kernel<<<qgrid, 256, 0, stream>>>(x, WT, out);
}

// Round 8
// 48.611 us; speedup vs baseline: 1.0577x; 1.0358x over previous
//
#include <hip/hip_runtime.h>
#include <hip/hip_bf16.h>

#define BATCH 8192
#define DDIM 512
#define FDIM 64
#define KD 64

typedef __attribute__((ext_vector_type(8))) short short8;
typedef __attribute__((ext_vector_type(4))) float f32x4;

static __device__ __forceinline__ unsigned short f2bf(float f) {
    __hip_bfloat16 h = __float2bfloat16(f);
    return *reinterpret_cast<unsigned short*>(&h);
}

// ---------------- W^T (bf16, N-major) + zero out ----------------
// Block per j. WT[j*D + i] = (i<j) ? dot(kernel[i,fd[j],:], kernel[j,fd[i],:]) : 0
__global__ __launch_bounds__(256) void w_kernel(const float* __restrict__ kern,
                                                const int* __restrict__ fd,
                                                unsigned short* __restrict__ WT,
                                                float* __restrict__ out) {
    const int j = blockIdx.x;
    const int tid = threadIdx.x;

    __shared__ float Bv[FDIM * KD];   // kernel[j,:,:]  (16 KB)
    __shared__ int fds[DDIM];

    if (tid < 16) out[j * 16 + tid] = 0.f;   // fold out-zeroing in (runs before quad)

    {
        const float4* src = reinterpret_cast<const float4*>(kern + (size_t)j * FDIM * KD);
        float4* dst = reinterpret_cast<float4*>(Bv);
#pragma unroll
        for (int u = 0; u < 4; ++u) dst[u * 256 + tid] = src[u * 256 + tid];
        fds[tid] = fd[tid];
        fds[tid + 256] = fd[tid + 256];
    }
    __syncthreads();

    const int fdj = fds[j];
    const int g = tid >> 4;    // 16-lane group -> one i per iteration
    const int gl = tid & 15;   // lane over k (4 floats each)

#pragma unroll 2
    for (int it = 0; it < DDIM / 16; ++it) {
        const int i = it * 16 + g;
        float s = 0.f;
        if (i < j) {
            float4 a = *reinterpret_cast<const float4*>(kern + ((size_t)i * FDIM + fdj) * KD + gl * 4);
            float4 b = *reinterpret_cast<const float4*>(Bv + fds[i] * KD + gl * 4);
            s = a.x * b.x + a.y * b.y + a.z * b.z + a.w * b.w;
        }
#pragma unroll
        for (int off = 1; off < 16; off <<= 1) s += __shfl_xor(s, off);
        if (gl == 0) WT[(size_t)j * DDIM + i] = f2bf(s);
    }
}

// ---------------- fused  out[b] = x[b,:] @ Wm @ x[b,:]  (MFMA bf16) ----------------
#define BM 64
#define BN 128
#define BK 64
#define NIT (DDIM / BK)

__global__ __launch_bounds__(256, 2) void quad_kernel(const float* __restrict__ x,
                                                      const unsigned short* __restrict__ WT,
                                                      float* __restrict__ out) {
    __shared__ unsigned short As[2][BM * BK];   // 16 KB  (16B-chunk XOR swizzle)
    __shared__ unsigned short Bs[2][BN * BK];   // 32 KB

    const int tid = threadIdx.x;
    const int lane = tid & 63;
    const int w = tid >> 6;
    const int wm = w >> 1, wn = w & 1;
    const int ln = lane & 15, l4 = lane >> 4;
    // XCD-coherent mapping: the 4 n-blocks sharing an m-panel get block ids
    // {m, m+128, m+256, m+384} — all ≡ m (mod 8) → same XCD L2 caches the x panel.
    const int mb = blockIdx.x & 127;
    const int nb = blockIdx.x >> 7;
    const int nbase = nb * BN;
    const int mbase = mb * BM;

    f32x4 acc[2][4] = {};

    const int srow = tid >> 2;   // 0..63
    const int sc = tid & 3;

    // Named double buffers: ALL indices compile-time (rule #20 — no scratch).
    float4 aregA[4], aregB[4];
    int4 bregA[4], bregB[4];

    auto loadTile = [&](int kk, float4 (&ar)[4], int4 (&br)[4]) {
        const float4* srcA = reinterpret_cast<const float4*>(x + (size_t)(mbase + srow) * DDIM + kk + sc * 16);
#pragma unroll
        for (int u = 0; u < 4; ++u) ar[u] = srcA[u];
#pragma unroll
        for (int r = 0; r < 2; ++r) {
            const int4* srcB = reinterpret_cast<const int4*>(WT + (size_t)(nbase + srow + r * 64) * DDIM + kk);
#pragma unroll
            for (int u = 0; u < 2; ++u) br[r * 2 + u] = srcB[sc * 2 + u];
        }
    };
    auto writeTile = [&](float4 (&ar)[4], int4 (&br)[4], unsigned short* Asb, unsigned short* Bsb) {
#pragma unroll
        for (int h = 0; h < 2; ++h) {
            float4 p = ar[2 * h], q = ar[2 * h + 1];
            short8 v;
            v[0] = (short)f2bf(p.x); v[1] = (short)f2bf(p.y);
            v[2] = (short)f2bf(p.z); v[3] = (short)f2bf(p.w);
            v[4] = (short)f2bf(q.x); v[5] = (short)f2bf(q.y);
            v[6] = (short)f2bf(q.z); v[7] = (short)f2bf(q.w);
            int chunk = (2 * sc + h) ^ (srow & 7);
            *reinterpret_cast<short8*>(Asb + srow * BK + chunk * 8) = v;
        }
#pragma unroll
        for (int r = 0; r < 2; ++r)
#pragma unroll
            for (int u = 0; u < 2; ++u) {
                int row = srow + r * 64;
                int chunk = (2 * sc + u) ^ (row & 7);
                *reinterpret_cast<int4*>(Bsb + row * BK + chunk * 8) = br[r * 2 + u];
            }
    };
    auto computeTile = [&](const unsigned short* Asb, const unsigned short* Bsb) {
        short8 a[2][2], b[2][4];
#pragma unroll
        for (int ks = 0; ks < 2; ++ks) {
#pragma unroll
            for (int m = 0; m < 2; ++m) {
                int row = wm * 32 + m * 16 + ln;
                int chunk = (ks * 4 + l4) ^ (row & 7);
                a[ks][m] = *reinterpret_cast<const short8*>(Asb + row * BK + chunk * 8);
            }
#pragma unroll
            for (int n = 0; n < 4; ++n) {
                int col = wn * 64 + n * 16 + ln;
                int chunk = (ks * 4 + l4) ^ (col & 7);
                b[ks][n] = *reinterpret_cast<const short8*>(Bsb + col * BK + chunk * 8);
            }
        }
#pragma unroll
        for (int ks = 0; ks < 2; ++ks)
#pragma unroll
            for (int m = 0; m < 2; ++m)
#pragma unroll
                for (int n = 0; n < 4; ++n)
                    acc[m][n] = __builtin_amdgcn_mfma_f32_16x16x32_bf16(a[ks][m], b[ks][n], acc[m][n], 0, 0, 0);
    };

    // prologue: tile0 -> regsA -> LDS0; tile1 -> regsB (in flight)
    loadTile(0, aregA, bregA);
    loadTile(BK, aregB, bregB);
    writeTile(aregA, bregA, &As[0][0], &Bs[0][0]);
    __syncthreads();

    for (int t = 0; t < NIT; t += 2) {
        // even step: compute LDS0(tile t); prefetch tile t+2 -> regsA; write regsB(tile t+1) -> LDS1
        if (t + 2 < NIT) loadTile((t + 2) * BK, aregA, bregA);
        computeTile(&As[0][0], &Bs[0][0]);
        if (t + 1 < NIT) writeTile(aregB, bregB, &As[1][0], &Bs[1][0]);
        __syncthreads();
        // odd step: compute LDS1(tile t+1); prefetch tile t+3 -> regsB; write regsA(tile t+2) -> LDS0
        if (t + 3 < NIT) loadTile((t + 3) * BK, aregB, bregB);
        computeTile(&As[1][0], &Bs[1][0]);
        if (t + 2 < NIT) writeTile(aregA, bregA, &As[0][0], &Bs[0][0]);
        __syncthreads();
    }

    // epilogue: out[row] += sum_col y[row][col] * x[row][col]
#pragma unroll
    for (int m = 0; m < 2; ++m) {
#pragma unroll
        for (int q = 0; q < 4; ++q) {
            int grow = mbase + wm * 32 + m * 16 + l4 * 4 + q;   // C/D: row=(lane>>4)*4+reg
            float s = 0.f;
#pragma unroll
            for (int n = 0; n < 4; ++n) {
                int gcol = nbase + wn * 64 + n * 16 + ln;        // C/D: col=lane&15
                s += acc[m][n][q] * x[(size_t)grow * DDIM + gcol];
            }
#pragma unroll
            for (int off = 1; off < 16; off <<= 1)
                s += __shfl_xor(s, off, 64);
            if (ln == 0) atomicAdd(out + grow, s);
        }
    }
}

extern "C" void kernel_launch(void* const* d_in, const int* in_sizes, int n_in,
                              void* d_out, int out_size, void* d_ws, size_t ws_size,
                              hipStream_t stream) {
    const float* x = (const float*)d_in[0];
    const float* kern = (const float*)d_in[1];
    const int* fd = (const int*)d_in[2];
    float* out = (float*)d_out;

    unsigned short* WT = (unsigned short*)d_ws;

    w_kernel<<<DDIM, 256, 0, stream>>>(kern, fd, WT, out);
    quad_kernel<<<512, 256, 0, stream>>>(x, WT, out);
}

// Round 10
// 36.363 us; speedup vs baseline: 1.4139x; 1.3368x over previous
//
#include <hip/hip_runtime.h>
#include <hip/hip_bf16.h>

#define BATCH 8192
#define DDIM 512
#define FDIM 64
#define KD 64

typedef __attribute__((ext_vector_type(8))) short short8;
typedef __attribute__((ext_vector_type(4))) float f32x4;

static __device__ __forceinline__ unsigned short f2bf(float f) {
    __hip_bfloat16 h = __float2bfloat16(f);
    return *reinterpret_cast<unsigned short*>(&h);
}

// ---------------- W^T (bf16, N-major) + zero out ----------------
// Block per j. WT[j*D + i] = (i<j) ? dot(kernel[i,fd[j],:], kernel[j,fd[i],:]) : 0
__global__ __launch_bounds__(256) void w_kernel(const float* __restrict__ kern,
                                                const int* __restrict__ fd,
                                                unsigned short* __restrict__ WT,
                                                float* __restrict__ out) {
    const int j = blockIdx.x;
    const int tid = threadIdx.x;

    __shared__ float Bv[FDIM * KD];   // kernel[j,:,:]  (16 KB)
    __shared__ int fds[DDIM];

    if (tid < 16) out[j * 16 + tid] = 0.f;   // fold out-zeroing in (runs before quad)

    {
        const float4* src = reinterpret_cast<const float4*>(kern + (size_t)j * FDIM * KD);
        float4* dst = reinterpret_cast<float4*>(Bv);
#pragma unroll
        for (int u = 0; u < 4; ++u) dst[u * 256 + tid] = src[u * 256 + tid];
        fds[tid] = fd[tid];
        fds[tid + 256] = fd[tid + 256];
    }
    __syncthreads();

    const int fdj = fds[j];
    const int g = tid >> 4;    // 16-lane group -> one i per iteration
    const int gl = tid & 15;   // lane over k (4 floats each)

#pragma unroll 2
    for (int it = 0; it < DDIM / 16; ++it) {
        const int i = it * 16 + g;
        float s = 0.f;
        if (i < j) {
            float4 a = *reinterpret_cast<const float4*>(kern + ((size_t)i * FDIM + fdj) * KD + gl * 4);
            float4 b = *reinterpret_cast<const float4*>(Bv + fds[i] * KD + gl * 4);
            s = a.x * b.x + a.y * b.y + a.z * b.z + a.w * b.w;
        }
#pragma unroll
        for (int off = 1; off < 16; off <<= 1) s += __shfl_xor(s, off);
        if (gl == 0) WT[(size_t)j * DDIM + i] = f2bf(s);
    }
}

// ---------------- fused  out[b] = x[b,:] @ Wm @ x[b,:]  (MFMA bf16) ----------------
// Max-occupancy variant: BK=32, single 12 KB LDS buffer, <=128 VGPR -> 4 blocks/CU.
#define BM 64
#define BN 128
#define BK 32
#define NIT (DDIM / BK)

__global__ __launch_bounds__(256, 4) void quad_kernel(const float* __restrict__ x,
                                                      const unsigned short* __restrict__ WT,
                                                      float* __restrict__ out) {
    __shared__ unsigned short As[BM * BK];   // 4 KB
    __shared__ unsigned short Bs[BN * BK];   // 8 KB

    const int tid = threadIdx.x;
    const int lane = tid & 63;
    const int w = tid >> 6;
    const int wm = w >> 1, wn = w & 1;
    const int ln = lane & 15, l4 = lane >> 4;
    // XCD-coherent mapping: the 4 n-blocks sharing an m-panel have ids ≡ m (mod 8).
    const int mb = blockIdx.x & 127;
    const int nb = blockIdx.x >> 7;
    const int nbase = nb * BN;
    const int mbase = mb * BM;

    f32x4 acc[2][4] = {};

    const int arow = tid >> 2, ac = tid & 3;    // A: row 0..63, 8-float chunk 0..3
    const int brow = tid >> 1, bh = tid & 1;    // B: row 0..127, 16-bf16 half 0..1

    // Named prefetch registers — all indices compile-time (rule #20).
    float4 aA0, aA1, aB0, aB1;
    int4 bA0, bA1, bB0, bB1;

    auto loadT = [&](int kk, float4& a0, float4& a1, int4& b0, int4& b1) {
        const float4* srcA = reinterpret_cast<const float4*>(x + (size_t)(mbase + arow) * DDIM + kk + ac * 8);
        a0 = srcA[0]; a1 = srcA[1];
        const int4* srcB = reinterpret_cast<const int4*>(WT + (size_t)(nbase + brow) * DDIM + kk + bh * 16);
        b0 = srcB[0]; b1 = srcB[1];
    };
    auto writeT = [&](float4& a0, float4& a1, int4& b0, int4& b1) {
        short8 v;
        v[0] = (short)f2bf(a0.x); v[1] = (short)f2bf(a0.y);
        v[2] = (short)f2bf(a0.z); v[3] = (short)f2bf(a0.w);
        v[4] = (short)f2bf(a1.x); v[5] = (short)f2bf(a1.y);
        v[6] = (short)f2bf(a1.z); v[7] = (short)f2bf(a1.w);
        int cs = ac ^ (arow & 3) ^ ((arow >> 2) & 3);
        *reinterpret_cast<short8*>(As + arow * BK + cs * 8) = v;
        int c0 = (bh * 2 + 0) ^ (brow & 3) ^ ((brow >> 2) & 3);
        int c1 = (bh * 2 + 1) ^ (brow & 3) ^ ((brow >> 2) & 3);
        *reinterpret_cast<int4*>(Bs + brow * BK + c0 * 8) = b0;
        *reinterpret_cast<int4*>(Bs + brow * BK + c1 * 8) = b1;
    };
    auto computeT = [&]() {
        short8 a[2], b[4];
#pragma unroll
        for (int m = 0; m < 2; ++m) {
            int row = wm * 32 + m * 16 + ln;
            int chunk = l4 ^ (row & 3) ^ ((row >> 2) & 3);
            a[m] = *reinterpret_cast<const short8*>(As + row * BK + chunk * 8);
        }
#pragma unroll
        for (int n = 0; n < 4; ++n) {
            int col = wn * 64 + n * 16 + ln;
            int chunk = l4 ^ (col & 3) ^ ((col >> 2) & 3);
            b[n] = *reinterpret_cast<const short8*>(Bs + col * BK + chunk * 8);
        }
#pragma unroll
        for (int m = 0; m < 2; ++m)
#pragma unroll
            for (int n = 0; n < 4; ++n)
                acc[m][n] = __builtin_amdgcn_mfma_f32_16x16x32_bf16(a[m], b[n], acc[m][n], 0, 0, 0);
    };

    loadT(0, aA0, aA1, bA0, bA1);
    for (int t = 0; t < NIT; t += 2) {
        // even: prefetch t+1 -> setB; publish setA(t); compute
        if (t + 1 < NIT) loadT((t + 1) * BK, aB0, aB1, bB0, bB1);
        __syncthreads();                 // prior compute done reading LDS
        writeT(aA0, aA1, bA0, bA1);
        __syncthreads();
        computeT();
        // odd: prefetch t+2 -> setA; publish setB(t+1); compute
        if (t + 2 < NIT) loadT((t + 2) * BK, aA0, aA1, bA0, bA1);
        __syncthreads();
        writeT(aB0, aB1, bB0, bB1);
        __syncthreads();
        computeT();
    }

    // epilogue: out[row] += sum_col y[row][col] * x[row][col]
#pragma unroll
    for (int m = 0; m < 2; ++m) {
#pragma unroll
        for (int q = 0; q < 4; ++q) {
            int grow = mbase + wm * 32 + m * 16 + l4 * 4 + q;   // C/D: row=(lane>>4)*4+reg
            float s = 0.f;
#pragma unroll
            for (int n = 0; n < 4; ++n) {
                int gcol = nbase + wn * 64 + n * 16 + ln;        // C/D: col=lane&15
                s += acc[m][n][q] * x[(size_t)grow * DDIM + gcol];
            }
#pragma unroll
            for (int off = 1; off < 16; off <<= 1)
                s += __shfl_xor(s, off, 64);
            if (ln == 0) atomicAdd(out + grow, s);
        }
    }
}

extern "C" void kernel_launch(void* const* d_in, const int* in_sizes, int n_in,
                              void* d_out, int out_size, void* d_ws, size_t ws_size,
                              hipStream_t stream) {
    const float* x = (const float*)d_in[0];
    const float* kern = (const float*)d_in[1];
    const int* fd = (const int*)d_in[2];
    float* out = (float*)d_out;

    unsigned short* WT = (unsigned short*)d_ws;

    w_kernel<<<DDIM, 256, 0, stream>>>(kern, fd, WT, out);
    quad_kernel<<<512, 256, 0, stream>>>(x, WT, out);
}

// Round 11
// 35.949 us; speedup vs baseline: 1.4302x; 1.0115x over previous
//
#include <hip/hip_runtime.h>
#include <hip/hip_bf16.h>

#define BATCH 8192
#define DDIM 512
#define FDIM 64
#define KD 64

typedef __attribute__((ext_vector_type(8))) short short8;
typedef __attribute__((ext_vector_type(4))) float f32x4;

static __device__ __forceinline__ unsigned short f2bf(float f) {
    __hip_bfloat16 h = __float2bfloat16(f);
    return *reinterpret_cast<unsigned short*>(&h);
}

// ---------------- W^T (bf16, N-major) + zero out ----------------
// Block per j. WT[j*D + i] = (i<j) ? dot(kernel[i,fd[j],:], kernel[j,fd[i],:]) : 0
__global__ __launch_bounds__(256) void w_kernel(const float* __restrict__ kern,
                                                const int* __restrict__ fd,
                                                unsigned short* __restrict__ WT,
                                                float* __restrict__ out) {
    const int j = blockIdx.x;
    const int tid = threadIdx.x;

    __shared__ float Bv[FDIM * KD];   // kernel[j,:,:]  (16 KB)
    __shared__ int fds[DDIM];

    if (tid < 16) out[j * 16 + tid] = 0.f;   // fold out-zeroing in (runs before quad)

    {
        const float4* src = reinterpret_cast<const float4*>(kern + (size_t)j * FDIM * KD);
        float4* dst = reinterpret_cast<float4*>(Bv);
#pragma unroll
        for (int u = 0; u < 4; ++u) dst[u * 256 + tid] = src[u * 256 + tid];
        fds[tid] = fd[tid];
        fds[tid + 256] = fd[tid + 256];
    }
    __syncthreads();

    const int fdj = fds[j];
    const int g = tid >> 4;    // 16-lane group -> one i per iteration
    const int gl = tid & 15;   // lane over k (4 floats each)

#pragma unroll 2
    for (int it = 0; it < DDIM / 16; ++it) {
        const int i = it * 16 + g;
        float s = 0.f;
        if (i < j) {
            float4 a = *reinterpret_cast<const float4*>(kern + ((size_t)i * FDIM + fdj) * KD + gl * 4);
            float4 b = *reinterpret_cast<const float4*>(Bv + fds[i] * KD + gl * 4);
            s = a.x * b.x + a.y * b.y + a.z * b.z + a.w * b.w;
        }
#pragma unroll
        for (int off = 1; off < 16; off <<= 1) s += __shfl_xor(s, off);
        if (gl == 0) WT[(size_t)j * DDIM + i] = f2bf(s);
    }
}

// ---------------- fused  out[b] = x[b,:] @ Wm @ x[b,:]  (MFMA bf16) ----------------
// Max-occupancy (r10 winner) + triangular K-cap: n-block nb only needs k < (nb+1)*BN
// (W is strictly upper-triangular; w_kernel wrote exact zeros at/below the diagonal).
#define BM 64
#define BN 128
#define BK 32

__global__ __launch_bounds__(256, 4) void quad_kernel(const float* __restrict__ x,
                                                      const unsigned short* __restrict__ WT,
                                                      float* __restrict__ out) {
    __shared__ unsigned short As[BM * BK];   // 4 KB
    __shared__ unsigned short Bs[BN * BK];   // 8 KB

    const int tid = threadIdx.x;
    const int lane = tid & 63;
    const int w = tid >> 6;
    const int wm = w >> 1, wn = w & 1;
    const int ln = lane & 15, l4 = lane >> 4;
    // m-major ids: blocks sharing an m-panel are ≡ m (mod 8) -> same XCD L2.
    // nb reversed so the LONG (nb=3, 16-step) blocks dispatch first; short ones pack the tail.
    const int mb = blockIdx.x & 127;
    const int nb = 3 - (blockIdx.x >> 7);
    const int nbase = nb * BN;
    const int mbase = mb * BM;

    // triangular cap: columns [nbase, nbase+BN) need k only up to nbase+BN
    const int ksteps = (nb + 1) * (BN / BK);   // 4, 8, 12, 16

    f32x4 acc[2][4] = {};

    const int arow = tid >> 2, ac = tid & 3;    // A: row 0..63, 8-float chunk 0..3
    const int brow = tid >> 1, bh = tid & 1;    // B: row 0..127, 16-bf16 half 0..1

    // Named prefetch registers — all indices compile-time (rule #20).
    float4 aA0, aA1, aB0, aB1;
    int4 bA0, bA1, bB0, bB1;

    auto loadT = [&](int kk, float4& a0, float4& a1, int4& b0, int4& b1) {
        const float4* srcA = reinterpret_cast<const float4*>(x + (size_t)(mbase + arow) * DDIM + kk + ac * 8);
        a0 = srcA[0]; a1 = srcA[1];
        const int4* srcB = reinterpret_cast<const int4*>(WT + (size_t)(nbase + brow) * DDIM + kk + bh * 16);
        b0 = srcB[0]; b1 = srcB[1];
    };
    auto writeT = [&](float4& a0, float4& a1, int4& b0, int4& b1) {
        short8 v;
        v[0] = (short)f2bf(a0.x); v[1] = (short)f2bf(a0.y);
        v[2] = (short)f2bf(a0.z); v[3] = (short)f2bf(a0.w);
        v[4] = (short)f2bf(a1.x); v[5] = (short)f2bf(a1.y);
        v[6] = (short)f2bf(a1.z); v[7] = (short)f2bf(a1.w);
        int cs = ac ^ (arow & 3) ^ ((arow >> 2) & 3);
        *reinterpret_cast<short8*>(As + arow * BK + cs * 8) = v;
        int c0 = (bh * 2 + 0) ^ (brow & 3) ^ ((brow >> 2) & 3);
        int c1 = (bh * 2 + 1) ^ (brow & 3) ^ ((brow >> 2) & 3);
        *reinterpret_cast<int4*>(Bs + brow * BK + c0 * 8) = b0;
        *reinterpret_cast<int4*>(Bs + brow * BK + c1 * 8) = b1;
    };
    auto computeT = [&]() {
        short8 a[2], b[4];
#pragma unroll
        for (int m = 0; m < 2; ++m) {
            int row = wm * 32 + m * 16 + ln;
            int chunk = l4 ^ (row & 3) ^ ((row >> 2) & 3);
            a[m] = *reinterpret_cast<const short8*>(As + row * BK + chunk * 8);
        }
#pragma unroll
        for (int n = 0; n < 4; ++n) {
            int col = wn * 64 + n * 16 + ln;
            int chunk = l4 ^ (col & 3) ^ ((col >> 2) & 3);
            b[n] = *reinterpret_cast<const short8*>(Bs + col * BK + chunk * 8);
        }
#pragma unroll
        for (int m = 0; m < 2; ++m)
#pragma unroll
            for (int n = 0; n < 4; ++n)
                acc[m][n] = __builtin_amdgcn_mfma_f32_16x16x32_bf16(a[m], b[n], acc[m][n], 0, 0, 0);
    };

    loadT(0, aA0, aA1, bA0, bA1);
    for (int t = 0; t < ksteps; t += 2) {
        // even: prefetch t+1 -> setB; publish setA(t); compute
        if (t + 1 < ksteps) loadT((t + 1) * BK, aB0, aB1, bB0, bB1);
        __syncthreads();                 // prior compute done reading LDS
        writeT(aA0, aA1, bA0, bA1);
        __syncthreads();
        computeT();
        // odd: prefetch t+2 -> setA; publish setB(t+1); compute
        if (t + 2 < ksteps) loadT((t + 2) * BK, aA0, aA1, bA0, bA1);
        __syncthreads();
        writeT(aB0, aB1, bB0, bB1);
        __syncthreads();
        computeT();
    }

    // epilogue: out[row] += sum_col y[row][col] * x[row][col]
#pragma unroll
    for (int m = 0; m < 2; ++m) {
#pragma unroll
        for (int q = 0; q < 4; ++q) {
            int grow = mbase + wm * 32 + m * 16 + l4 * 4 + q;   // C/D: row=(lane>>4)*4+reg
            float s = 0.f;
#pragma unroll
            for (int n = 0; n < 4; ++n) {
                int gcol = nbase + wn * 64 + n * 16 + ln;        // C/D: col=lane&15
                s += acc[m][n][q] * x[(size_t)grow * DDIM + gcol];
            }
#pragma unroll
            for (int off = 1; off < 16; off <<= 1)
                s += __shfl_xor(s, off, 64);
            if (ln == 0) atomicAdd(out + grow, s);
        }
    }
}

extern "C" void kernel_launch(void* const* d_in, const int* in_sizes, int n_in,
                              void* d_out, int out_size, void* d_ws, size_t ws_size,
                              hipStream_t stream) {
    const float* x = (const float*)d_in[0];
    const float* kern = (const float*)d_in[1];
    const int* fd = (const int*)d_in[2];
    float* out = (float*)d_out;

    unsigned short* WT = (unsigned short*)d_ws;

    w_kernel<<<DDIM, 256, 0, stream>>>(kern, fd, WT, out);
    quad_kernel<<<512, 256, 0, stream>>>(x, WT, out);
}

// Round 12
// 33.464 us; speedup vs baseline: 1.5364x; 1.0743x over previous
//
#include <hip/hip_runtime.h>
#include <hip/hip_bf16.h>

#define BATCH 8192
#define DDIM 512
#define FDIM 64
#define KD 64

typedef __attribute__((ext_vector_type(8))) short short8;
typedef __attribute__((ext_vector_type(4))) float f32x4;

static __device__ __forceinline__ unsigned short f2bf(float f) {
    __hip_bfloat16 h = __float2bfloat16(f);
    return *reinterpret_cast<unsigned short*>(&h);
}

// ---------------- W^T (bf16, N-major) + zero out ----------------
// Block per j. WT[j*D + i] = (i<j) ? dot(kernel[i,fd[j],:], kernel[j,fd[i],:]) : 0
__global__ __launch_bounds__(256) void w_kernel(const float* __restrict__ kern,
                                                const int* __restrict__ fd,
                                                unsigned short* __restrict__ WT,
                                                float* __restrict__ out) {
    const int j = blockIdx.x;
    const int tid = threadIdx.x;

    __shared__ float Bv[FDIM * KD];   // kernel[j,:,:]  (16 KB)
    __shared__ int fds[DDIM];

    if (tid < 16) out[j * 16 + tid] = 0.f;   // fold out-zeroing in (runs before quad)

    {
        const float4* src = reinterpret_cast<const float4*>(kern + (size_t)j * FDIM * KD);
        float4* dst = reinterpret_cast<float4*>(Bv);
#pragma unroll
        for (int u = 0; u < 4; ++u) dst[u * 256 + tid] = src[u * 256 + tid];
        fds[tid] = fd[tid];
        fds[tid + 256] = fd[tid + 256];
    }
    __syncthreads();

    const int fdj = fds[j];
    const int g = tid >> 4;    // 16-lane group -> one i per iteration
    const int gl = tid & 15;   // lane over k (4 floats each)

#pragma unroll 2
    for (int it = 0; it < DDIM / 16; ++it) {
        const int i = it * 16 + g;
        float s = 0.f;
        if (i < j) {
            float4 a = *reinterpret_cast<const float4*>(kern + ((size_t)i * FDIM + fdj) * KD + gl * 4);
            float4 b = *reinterpret_cast<const float4*>(Bv + fds[i] * KD + gl * 4);
            s = a.x * b.x + a.y * b.y + a.z * b.z + a.w * b.w;
        }
#pragma unroll
        for (int off = 1; off < 16; off <<= 1) s += __shfl_xor(s, off);
        if (gl == 0) WT[(size_t)j * DDIM + i] = f2bf(s);
    }
}

// ---------------- fused  out[b] = x[b,:] @ Wm @ x[b,:]  (MFMA bf16) ----------------
// Balanced triangular decomposition: each block owns (m-panel, n-panel nb, k-chunk)
// with a FIXED 4-step (128-wide) k-chunk. Panel nb has nb+1 chunks -> 10 chunks
// per m-panel -> 1280 equal-work blocks (4 resident/CU). Partial epilogue sums
// accumulate via atomicAdd.
#define BM 64
#define BN 128
#define BK 32
#define KSTEPS 4

__global__ __launch_bounds__(256, 4) void quad_kernel(const float* __restrict__ x,
                                                      const unsigned short* __restrict__ WT,
                                                      float* __restrict__ out) {
    __shared__ unsigned short As[BM * BK];   // 4 KB
    __shared__ unsigned short Bs[BN * BK];   // 8 KB

    const int tid = threadIdx.x;
    const int lane = tid & 63;
    const int w = tid >> 6;
    const int wm = w >> 1, wn = w & 1;
    const int ln = lane & 15, l4 = lane >> 4;

    // id = c*128 + m : m-sharing blocks are ≡ m (mod 8) -> same XCD L2 for the x panel.
    const int mb = blockIdx.x & 127;
    const int c = blockIdx.x >> 7;            // 0..9
    const int nb = (c >= 1) + (c >= 3) + (c >= 6);
    const int chunk = c - nb * (nb + 1) / 2;
    const int nbase = nb * BN;
    const int mbase = mb * BM;
    const int kbase = chunk * (KSTEPS * BK);  // 128-wide k-chunk

    f32x4 acc[2][4] = {};

    const int arow = tid >> 2, ac = tid & 3;    // A: row 0..63, 8-float chunk 0..3
    const int brow = tid >> 1, bh = tid & 1;    // B: row 0..127, 16-bf16 half 0..1

    // Named prefetch registers — all indices compile-time (rule #20).
    float4 aA0, aA1, aB0, aB1;
    int4 bA0, bA1, bB0, bB1;

    auto loadT = [&](int kk, float4& a0, float4& a1, int4& b0, int4& b1) {
        const float4* srcA = reinterpret_cast<const float4*>(x + (size_t)(mbase + arow) * DDIM + kk + ac * 8);
        a0 = srcA[0]; a1 = srcA[1];
        const int4* srcB = reinterpret_cast<const int4*>(WT + (size_t)(nbase + brow) * DDIM + kk + bh * 16);
        b0 = srcB[0]; b1 = srcB[1];
    };
    auto writeT = [&](float4& a0, float4& a1, int4& b0, int4& b1) {
        short8 v;
        v[0] = (short)f2bf(a0.x); v[1] = (short)f2bf(a0.y);
        v[2] = (short)f2bf(a0.z); v[3] = (short)f2bf(a0.w);
        v[4] = (short)f2bf(a1.x); v[5] = (short)f2bf(a1.y);
        v[6] = (short)f2bf(a1.z); v[7] = (short)f2bf(a1.w);
        int cs = ac ^ (arow & 3) ^ ((arow >> 2) & 3);
        *reinterpret_cast<short8*>(As + arow * BK + cs * 8) = v;
        int c0 = (bh * 2 + 0) ^ (brow & 3) ^ ((brow >> 2) & 3);
        int c1 = (bh * 2 + 1) ^ (brow & 3) ^ ((brow >> 2) & 3);
        *reinterpret_cast<int4*>(Bs + brow * BK + c0 * 8) = b0;
        *reinterpret_cast<int4*>(Bs + brow * BK + c1 * 8) = b1;
    };
    auto computeT = [&]() {
        short8 a[2], b[4];
#pragma unroll
        for (int m = 0; m < 2; ++m) {
            int row = wm * 32 + m * 16 + ln;
            int ch = l4 ^ (row & 3) ^ ((row >> 2) & 3);
            a[m] = *reinterpret_cast<const short8*>(As + row * BK + ch * 8);
        }
#pragma unroll
        for (int n = 0; n < 4; ++n) {
            int col = wn * 64 + n * 16 + ln;
            int ch = l4 ^ (col & 3) ^ ((col >> 2) & 3);
            b[n] = *reinterpret_cast<const short8*>(Bs + col * BK + ch * 8);
        }
#pragma unroll
        for (int m = 0; m < 2; ++m)
#pragma unroll
            for (int n = 0; n < 4; ++n)
                acc[m][n] = __builtin_amdgcn_mfma_f32_16x16x32_bf16(a[m], b[n], acc[m][n], 0, 0, 0);
    };

    loadT(kbase, aA0, aA1, bA0, bA1);
#pragma unroll
    for (int t = 0; t < KSTEPS; t += 2) {
        // even: prefetch t+1 -> setB; publish setA(t); compute
        if (t + 1 < KSTEPS) loadT(kbase + (t + 1) * BK, aB0, aB1, bB0, bB1);
        __syncthreads();                 // prior compute done reading LDS
        writeT(aA0, aA1, bA0, bA1);
        __syncthreads();
        computeT();
        // odd: prefetch t+2 -> setA; publish setB(t+1); compute
        if (t + 2 < KSTEPS) loadT(kbase + (t + 2) * BK, aA0, aA1, bA0, bA1);
        __syncthreads();
        writeT(aB0, aB1, bB0, bB1);
        __syncthreads();
        computeT();
    }

    // epilogue: out[row] += sum_col y_partial[row][col] * x[row][col]
#pragma unroll
    for (int m = 0; m < 2; ++m) {
#pragma unroll
        for (int q = 0; q < 4; ++q) {
            int grow = mbase + wm * 32 + m * 16 + l4 * 4 + q;   // C/D: row=(lane>>4)*4+reg
            float s = 0.f;
#pragma unroll
            for (int n = 0; n < 4; ++n) {
                int gcol = nbase + wn * 64 + n * 16 + ln;        // C/D: col=lane&15
                s += acc[m][n][q] * x[(size_t)grow * DDIM + gcol];
            }
#pragma unroll
            for (int off = 1; off < 16; off <<= 1)
                s += __shfl_xor(s, off, 64);
            if (ln == 0) atomicAdd(out + grow, s);
        }
    }
}

extern "C" void kernel_launch(void* const* d_in, const int* in_sizes, int n_in,
                              void* d_out, int out_size, void* d_ws, size_t ws_size,
                              hipStream_t stream) {
    const float* x = (const float*)d_in[0];
    const float* kern = (const float*)d_in[1];
    const int* fd = (const int*)d_in[2];
    float* out = (float*)d_out;

    unsigned short* WT = (unsigned short*)d_ws;

    w_kernel<<<DDIM, 256, 0, stream>>>(kern, fd, WT, out);
    quad_kernel<<<1280, 256, 0, stream>>>(x, WT, out);
}

// Round 15
// 28.336 us; speedup vs baseline: 1.8144x; 1.1810x over previous
//
#include <hip/hip_runtime.h>
#include <hip/hip_bf16.h>

#define BATCH 8192
#define DDIM 512
#define FDIM 64
#define KD 64

typedef __attribute__((ext_vector_type(8))) short short8;
typedef __attribute__((ext_vector_type(4))) float f32x4;

static __device__ __forceinline__ unsigned short f2bf(float f) {
    __hip_bfloat16 h = __float2bfloat16(f);
    return *reinterpret_cast<unsigned short*>(&h);
}

static __device__ __forceinline__ void gll16(const void* g, void* l) {
    __builtin_amdgcn_global_load_lds(
        (const __attribute__((address_space(1))) void*)g,
        (__attribute__((address_space(3))) void*)l, 16, 0, 0);
}

// ---------------- W^T (bf16, N-major) + x->bf16 + zero out ----------------
// Grid (iq=4, j=512). Block (j,iq): WT[j, iq*128 .. iq*128+128) and one
// 2048-float slice of x (total: 2048 blocks x 2048 = 4.19M floats, exact).
__global__ __launch_bounds__(256) void w_kernel(const float* __restrict__ kern,
                                                const int* __restrict__ fd,
                                                const float* __restrict__ x,
                                                unsigned short* __restrict__ WT,
                                                unsigned short* __restrict__ xb,
                                                float* __restrict__ out) {
    const int iq = blockIdx.x;        // 0..3
    const int j = blockIdx.y;         // 0..511
    const int tid = threadIdx.x;

    // ---- x -> bf16: one 2048-float slice, 8 floats/thread ----
    {
        const size_t base = ((size_t)j * 4 + iq) * 2048;
        const float4* X4 = reinterpret_cast<const float4*>(x + base);
        float4 p = X4[tid * 2];
        float4 q = X4[tid * 2 + 1];
        short8 v;
        v[0] = (short)f2bf(p.x); v[1] = (short)f2bf(p.y);
        v[2] = (short)f2bf(p.z); v[3] = (short)f2bf(p.w);
        v[4] = (short)f2bf(q.x); v[5] = (short)f2bf(q.y);
        v[6] = (short)f2bf(q.z); v[7] = (short)f2bf(q.w);
        *reinterpret_cast<short8*>(xb + base + tid * 8) = v;
    }

    if (iq == 0 && tid < 16) out[j * 16 + tid] = 0.f;   // zero out (runs before quad)

    const int ibase = iq * 128;
    if (ibase >= j) {
        // whole i-range >= j: exact zeros
        if (tid < 16) {
            short8 z = {};
            *reinterpret_cast<short8*>(WT + (size_t)j * DDIM + ibase + tid * 8) = z;
        }
        return;
    }

    __shared__ float Bv[FDIM * KD];   // kernel[j,:,:]  (16 KB)
    __shared__ int fds[DDIM];
    {
        const float4* src = reinterpret_cast<const float4*>(kern + (size_t)j * FDIM * KD);
        float4* dst = reinterpret_cast<float4*>(Bv);
#pragma unroll
        for (int u = 0; u < 4; ++u) dst[u * 256 + tid] = src[u * 256 + tid];
        fds[tid] = fd[tid];
        fds[tid + 256] = fd[tid + 256];
    }
    __syncthreads();

    const int fdj = fds[j];
    const int g = tid >> 4;    // 16-lane group -> one i per iteration
    const int gl = tid & 15;   // lane over k (4 floats each)

#pragma unroll 4
    for (int it = 0; it < 8; ++it) {
        const int i = ibase + it * 16 + g;
        float s = 0.f;
        if (i < j) {
            float4 a = *reinterpret_cast<const float4*>(kern + ((size_t)i * FDIM + fdj) * KD + gl * 4);
            float4 b = *reinterpret_cast<const float4*>(Bv + fds[i] * KD + gl * 4);
            s = a.x * b.x + a.y * b.y + a.z * b.z + a.w * b.w;
        }
#pragma unroll
        for (int off = 1; off < 16; off <<= 1) s += __shfl_xor(s, off);
        if (gl == 0) WT[(size_t)j * DDIM + i] = f2bf(s);
    }
}

// ---------------- fused  out[b] = x[b,:] @ Wm @ x[b,:]  (MFMA bf16) ----------------
// Balanced triangle (r12) + global_load_lds staging from pre-converted xb/WT into
// LINEAR double-buffered LDS (gll dest = wave-uniform base + lane*16; linear frag
// reads are <=2-way bank aliases here, ~free per m136).
#define BM 64
#define BN 128
#define BK 32
#define KSTEPS 4

__global__ __launch_bounds__(256, 4) void quad_kernel(const unsigned short* __restrict__ xb,
                                                      const unsigned short* __restrict__ WT,
                                                      const float* __restrict__ x,
                                                      float* __restrict__ out) {
    __shared__ unsigned short As[2][BM * BK];   // 2 x 4 KB, linear [row][k]
    __shared__ unsigned short Bs[2][BN * BK];   // 2 x 8 KB, linear [col][k]

    const int tid = threadIdx.x;
    const int lane = tid & 63;
    const int w = tid >> 6;
    const int wm = w >> 1, wn = w & 1;
    const int ln = lane & 15, l4 = lane >> 4;

    // id = c*128 + m : m-sharing blocks are ≡ m (mod 8) -> same XCD L2.
    const int mb = blockIdx.x & 127;
    const int c = blockIdx.x >> 7;            // 0..9
    const int nb = (c >= 1) + (c >= 3) + (c >= 6);
    const int chunk = c - nb * (nb + 1) / 2;
    const int nbase = nb * BN;
    const int mbase = mb * BM;
    const int kbase = chunk * (KSTEPS * BK);

    f32x4 acc[2][4] = {};

    const int srow = tid >> 2;       // 0..63
    const int sk = (tid & 3) * 8;    // k offset (elements) of this thread's 16B

    auto stage = [&](int kk, int buf) {
        // A: 64 rows x 32 k (4 KB) — dest bytes = tid*16
        gll16(xb + (size_t)(mbase + srow) * DDIM + kk + sk, &As[buf][tid * 8]);
        // B: 128 cols x 32 k (8 KB) — two 4 KB halves (dest index in SHORTS)
        gll16(WT + (size_t)(nbase + srow) * DDIM + kk + sk, &Bs[buf][tid * 8]);
        gll16(WT + (size_t)(nbase + 64 + srow) * DDIM + kk + sk, &Bs[buf][2048 + tid * 8]);
    };
    auto compute = [&](int buf) {
        short8 a[2], b[4];
#pragma unroll
        for (int m = 0; m < 2; ++m) {
            int row = wm * 32 + m * 16 + ln;
            a[m] = *reinterpret_cast<const short8*>(&As[buf][row * BK + l4 * 8]);
        }
#pragma unroll
        for (int n = 0; n < 4; ++n) {
            int col = wn * 64 + n * 16 + ln;
            b[n] = *reinterpret_cast<const short8*>(&Bs[buf][col * BK + l4 * 8]);
        }
#pragma unroll
        for (int m = 0; m < 2; ++m)
#pragma unroll
            for (int n = 0; n < 4; ++n)
                acc[m][n] = __builtin_amdgcn_mfma_f32_16x16x32_bf16(a[m], b[n], acc[m][n], 0, 0, 0);
    };

    stage(kbase, 0);
    __syncthreads();                       // vmcnt drain: buf0 ready
    stage(kbase + BK, 1);                  // t=1 in flight
    compute(0);
    __syncthreads();                       // buf1 ready, buf0 free
    stage(kbase + 2 * BK, 0);
    compute(1);
    __syncthreads();
    stage(kbase + 3 * BK, 1);
    compute(0);
    __syncthreads();
    compute(1);

    // epilogue: out[row] += sum_col y_partial[row][col] * x[row][col]  (f32 x)
#pragma unroll
    for (int m = 0; m < 2; ++m) {
#pragma unroll
        for (int q = 0; q < 4; ++q) {
            int grow = mbase + wm * 32 + m * 16 + l4 * 4 + q;   // C/D: row=(lane>>4)*4+reg
            float s = 0.f;
#pragma unroll
            for (int n = 0; n < 4; ++n) {
                int gcol = nbase + wn * 64 + n * 16 + ln;        // C/D: col=lane&15
                s += acc[m][n][q] * x[(size_t)grow * DDIM + gcol];
            }
#pragma unroll
            for (int off = 1; off < 16; off <<= 1)
                s += __shfl_xor(s, off, 64);
            if (ln == 0) atomicAdd(out + grow, s);
        }
    }
}

extern "C" void kernel_launch(void* const* d_in, const int* in_sizes, int n_in,
                              void* d_out, int out_size, void* d_ws, size_t ws_size,
                              hipStream_t stream) {
    const float* x = (const float*)d_in[0];
    const float* kern = (const float*)d_in[1];
    const int* fd = (const int*)d_in[2];
    float* out = (float*)d_out;

    unsigned short* WT = (unsigned short*)d_ws;                      // 512 KB
    unsigned short* xb = WT + (size_t)DDIM * DDIM;                   // 8 MB

    dim3 wgrid(4, DDIM);
    w_kernel<<<wgrid, 256, 0, stream>>>(kern, fd, x, WT, xb, out);
    quad_kernel<<<1280, 256, 0, stream>>>(xb, WT, x, out);
}

// Round 16
// 27.824 us; speedup vs baseline: 1.8478x; 1.0184x over previous
//
#include <hip/hip_runtime.h>
#include <hip/hip_bf16.h>

#define BATCH 8192
#define DDIM 512
#define FDIM 64
#define KD 64

typedef __attribute__((ext_vector_type(8))) short short8;
typedef __attribute__((ext_vector_type(4))) float f32x4;

static __device__ __forceinline__ unsigned short f2bf(float f) {
    __hip_bfloat16 h = __float2bfloat16(f);
    return *reinterpret_cast<unsigned short*>(&h);
}
static __device__ __forceinline__ float bf2f(unsigned short s) {
    union { unsigned int u; float f; } c;
    c.u = ((unsigned int)s) << 16;
    return c.f;
}

static __device__ __forceinline__ void gll16(const void* g, void* l) {
    __builtin_amdgcn_global_load_lds(
        (const __attribute__((address_space(1))) void*)g,
        (__attribute__((address_space(3))) void*)l, 16, 0, 0);
}

// ---------------- W^T (bf16, N-major) + x->bf16 + zero out ----------------
// Grid (iq=4, j=512). Block (j,iq): WT[j, iq*128 .. iq*128+128) and one
// 2048-float slice of x (2048 blocks x 2048 floats = 4.19M, exact).
__global__ __launch_bounds__(256) void w_kernel(const float* __restrict__ kern,
                                                const int* __restrict__ fd,
                                                const float* __restrict__ x,
                                                unsigned short* __restrict__ WT,
                                                unsigned short* __restrict__ xb,
                                                float* __restrict__ out) {
    const int iq = blockIdx.x;        // 0..3
    const int j = blockIdx.y;         // 0..511
    const int tid = threadIdx.x;

    // ---- x -> bf16: one 2048-float slice, 8 floats/thread ----
    {
        const size_t base = ((size_t)j * 4 + iq) * 2048;
        const float4* X4 = reinterpret_cast<const float4*>(x + base);
        float4 p = X4[tid * 2];
        float4 q = X4[tid * 2 + 1];
        short8 v;
        v[0] = (short)f2bf(p.x); v[1] = (short)f2bf(p.y);
        v[2] = (short)f2bf(p.z); v[3] = (short)f2bf(p.w);
        v[4] = (short)f2bf(q.x); v[5] = (short)f2bf(q.y);
        v[6] = (short)f2bf(q.z); v[7] = (short)f2bf(q.w);
        *reinterpret_cast<short8*>(xb + base + tid * 8) = v;
    }

    if (iq == 0 && tid < 16) out[j * 16 + tid] = 0.f;   // zero out (runs before quad)

    const int ibase = iq * 128;
    if (ibase >= j) {
        // whole i-range >= j: exact zeros
        if (tid < 16) {
            short8 z = {};
            *reinterpret_cast<short8*>(WT + (size_t)j * DDIM + ibase + tid * 8) = z;
        }
        return;
    }

    __shared__ float Bv[FDIM * KD];   // kernel[j,:,:]  (16 KB)
    __shared__ int fds[128];          // fd[ibase .. ibase+128)
    {
        const float4* src = reinterpret_cast<const float4*>(kern + (size_t)j * FDIM * KD);
        float4* dst = reinterpret_cast<float4*>(Bv);
#pragma unroll
        for (int u = 0; u < 4; ++u) dst[u * 256 + tid] = src[u * 256 + tid];
        if (tid < 128) fds[tid] = fd[ibase + tid];
    }
    const int fdj = fd[j];
    __syncthreads();

    const int g = tid >> 4;    // 16-lane group -> one i per iteration
    const int gl = tid & 15;   // lane over k (4 floats each)

#pragma unroll 8
    for (int it = 0; it < 8; ++it) {
        const int i = ibase + it * 16 + g;
        float s = 0.f;
        if (i < j) {
            float4 a = *reinterpret_cast<const float4*>(kern + ((size_t)i * FDIM + fdj) * KD + gl * 4);
            float4 b = *reinterpret_cast<const float4*>(Bv + fds[it * 16 + g] * KD + gl * 4);
            s = a.x * b.x + a.y * b.y + a.z * b.z + a.w * b.w;
        }
#pragma unroll
        for (int off = 1; off < 16; off <<= 1) s += __shfl_xor(s, off);
        if (gl == 0) WT[(size_t)j * DDIM + i] = f2bf(s);
    }
}

// ---------------- fused  out[b] = x[b,:] @ Wm @ x[b,:]  (MFMA bf16) ----------------
// Balanced triangle + global_load_lds staging into LINEAR double-buffered LDS.
#define BM 64
#define BN 128
#define BK 32
#define KSTEPS 4

__global__ __launch_bounds__(256, 4) void quad_kernel(const unsigned short* __restrict__ xb,
                                                      const unsigned short* __restrict__ WT,
                                                      float* __restrict__ out) {
    __shared__ unsigned short As[2][BM * BK];   // 2 x 4 KB, linear [row][k]
    __shared__ unsigned short Bs[2][BN * BK];   // 2 x 8 KB, linear [col][k]

    const int tid = threadIdx.x;
    const int lane = tid & 63;
    const int w = tid >> 6;
    const int wm = w >> 1, wn = w & 1;
    const int ln = lane & 15, l4 = lane >> 4;

    // id = c*128 + m : m-sharing blocks are ≡ m (mod 8) -> same XCD L2.
    const int mb = blockIdx.x & 127;
    const int c = blockIdx.x >> 7;            // 0..9
    const int nb = (c >= 1) + (c >= 3) + (c >= 6);
    const int chunk = c - nb * (nb + 1) / 2;
    const int nbase = nb * BN;
    const int mbase = mb * BM;
    const int kbase = chunk * (KSTEPS * BK);

    f32x4 acc[2][4] = {};

    const int srow = tid >> 2;       // 0..63
    const int sk = (tid & 3) * 8;    // k offset (elements) of this thread's 16B

    auto stage = [&](int kk, int buf) {
        gll16(xb + (size_t)(mbase + srow) * DDIM + kk + sk, &As[buf][tid * 8]);
        gll16(WT + (size_t)(nbase + srow) * DDIM + kk + sk, &Bs[buf][tid * 8]);
        gll16(WT + (size_t)(nbase + 64 + srow) * DDIM + kk + sk, &Bs[buf][2048 + tid * 8]);
    };
    auto compute = [&](int buf) {
        short8 a[2], b[4];
#pragma unroll
        for (int m = 0; m < 2; ++m) {
            int row = wm * 32 + m * 16 + ln;
            a[m] = *reinterpret_cast<const short8*>(&As[buf][row * BK + l4 * 8]);
        }
#pragma unroll
        for (int n = 0; n < 4; ++n) {
            int col = wn * 64 + n * 16 + ln;
            b[n] = *reinterpret_cast<const short8*>(&Bs[buf][col * BK + l4 * 8]);
        }
#pragma unroll
        for (int m = 0; m < 2; ++m)
#pragma unroll
            for (int n = 0; n < 4; ++n)
                acc[m][n] = __builtin_amdgcn_mfma_f32_16x16x32_bf16(a[m], b[n], acc[m][n], 0, 0, 0);
    };

    stage(kbase, 0);
    __syncthreads();                       // buf0 ready
    stage(kbase + BK, 1);                  // t=1 in flight under compute(0)
    compute(0);
    __syncthreads();                       // buf1 ready, buf0 free
    stage(kbase + 2 * BK, 0);
    compute(1);
    __syncthreads();
    stage(kbase + 3 * BK, 1);
    compute(0);
    __syncthreads();
    compute(1);

    // epilogue: out[row] += sum_col y_partial[row][col] * xb[row][col]
#pragma unroll
    for (int m = 0; m < 2; ++m) {
#pragma unroll
        for (int q = 0; q < 4; ++q) {
            int grow = mbase + wm * 32 + m * 16 + l4 * 4 + q;   // C/D: row=(lane>>4)*4+reg
            float s = 0.f;
#pragma unroll
            for (int n = 0; n < 4; ++n) {
                int gcol = nbase + wn * 64 + n * 16 + ln;        // C/D: col=lane&15
                s += acc[m][n][q] * bf2f(xb[(size_t)grow * DDIM + gcol]);
            }
#pragma unroll
            for (int off = 1; off < 16; off <<= 1)
                s += __shfl_xor(s, off, 64);
            if (ln == 0) atomicAdd(out + grow, s);
        }
    }
}

extern "C" void kernel_launch(void* const* d_in, const int* in_sizes, int n_in,
                              void* d_out, int out_size, void* d_ws, size_t ws_size,
                              hipStream_t stream) {
    const float* x = (const float*)d_in[0];
    const float* kern = (const float*)d_in[1];
    const int* fd = (const int*)d_in[2];
    float* out = (float*)d_out;

    unsigned short* WT = (unsigned short*)d_ws;                      // 512 KB
    unsigned short* xb = WT + (size_t)DDIM * DDIM;                   // 8 MB

    dim3 wgrid(4, DDIM);
    w_kernel<<<wgrid, 256, 0, stream>>>(kern, fd, x, WT, xb, out);
    quad_kernel<<<1280, 256, 0, stream>>>(xb, WT, out);
}